// Round 1
// baseline (250.905 us; speedup 1.0000x reference)
//
#include <hip/hip_runtime.h>

#define CB 256   // batch
#define CR 1152  // routes (primary caps)
#define CC 10    // class capsules
#define CO 16    // out dim
#define CI 8     // in dim
#define RS 48            // r-split factor for k_s
#define RCHUNK (CR/RS)   // 24 rows per block

// ---------------- transpose x[b][r][i] -> xT[r][b][i] ----------------
__global__ __launch_bounds__(256) void k_transpose_x(const float* __restrict__ x,
                                                     float* __restrict__ xT) {
  int idx = blockIdx.x * 256 + threadIdx.x;   // over B*R*2 float4s
  if (idx < CB * CR * 2) {
    int ih = idx & 1;
    int rem = idx >> 1;          // b*R + r
    int r = rem % CR, b = rem / CR;
    float4 val = ((const float4*)x)[idx];
    ((float4*)xT)[(r * CB + b) * 2 + ih] = val;
  }
}

// ---------------- s-pass: part[rs][b][c][o] = sum_{r in chunk} c_ij[r,c] * (W[r,c,o,:].x[b,r,:]) ----
// grid (C, RS), block 256 = 64 b-slots(x4) * 4 o-slots(x4). MODE0: c_ij = 1/C.
template<int MODE>
__global__ __launch_bounds__(256) void k_s(const float* __restrict__ xT,
                                           const float* __restrict__ W,
                                           const float* __restrict__ b_ij,
                                           float* __restrict__ part) {
  const int c  = blockIdx.x;
  const int rs = blockIdx.y;
  const int r0 = rs * RCHUNK;
  const int t  = threadIdx.x;
  const int os = t & 3;        // o-slot fastest -> store coalescing
  const int bs = t >> 2;
  const int b0 = bs * 4;
  const int o0 = os * 4;

  __shared__ float cs[RCHUNK];
  if (t < RCHUNK) {
    if (MODE == 0) {
      cs[t] = 1.0f / CC;
    } else {
      const float* bp = b_ij + (r0 + t) * CC;
      float m = bp[0];
      #pragma unroll
      for (int k = 1; k < CC; ++k) m = fmaxf(m, bp[k]);
      float sum = 0.f;
      #pragma unroll
      for (int k = 0; k < CC; ++k) sum += __expf(bp[k] - m);
      cs[t] = __expf(bp[c] - m) / sum;
    }
  }
  __syncthreads();

  float acc[4][4];
  #pragma unroll
  for (int a = 0; a < 4; ++a)
    #pragma unroll
    for (int d = 0; d < 4; ++d) acc[a][d] = 0.f;

  for (int j = 0; j < RCHUNK; ++j) {
    const int r = r0 + j;
    const float cw = cs[j];
    float4 wf[8], xf[8];
    const float4* wp = (const float4*)(W + (((size_t)r * CC + c) * CO + o0) * CI);
    const float4* xp = (const float4*)(xT + ((size_t)r * CB + b0) * CI);
    #pragma unroll
    for (int q = 0; q < 8; ++q) wf[q] = wp[q];   // 4 o x 8 i (wave-broadcast)
    #pragma unroll
    for (int q = 0; q < 8; ++q) xf[q] = xp[q];   // 4 b x 8 i (coalesced)
    #pragma unroll
    for (int db = 0; db < 4; ++db) {
      const float4 a0 = xf[2*db], a1 = xf[2*db+1];
      #pragma unroll
      for (int dd = 0; dd < 4; ++dd) {
        const float4 w0 = wf[2*dd], w1 = wf[2*dd+1];
        float d = a0.x * w0.x;
        d = fmaf(a0.y, w0.y, d);
        d = fmaf(a0.z, w0.z, d);
        d = fmaf(a0.w, w0.w, d);
        d = fmaf(a1.x, w1.x, d);
        d = fmaf(a1.y, w1.y, d);
        d = fmaf(a1.z, w1.z, d);
        d = fmaf(a1.w, w1.w, d);
        acc[db][dd] = fmaf(cw, d, acc[db][dd]);
      }
    }
  }

  #pragma unroll
  for (int db = 0; db < 4; ++db)
    #pragma unroll
    for (int dd = 0; dd < 4; ++dd)
      part[(((size_t)rs * CB + (b0 + db)) * CC + c) * CO + (o0 + dd)] = acc[db][dd];
}

// ---------------- squash: reduce partials + bias, v = s*n2/(1+n2)/sqrt(n2+eps) ----------------
template<bool LAST>
__global__ __launch_bounds__(256) void k_squash(const float* __restrict__ part,
                                                const float* __restrict__ bias,
                                                float* __restrict__ vT,
                                                float* __restrict__ out) {
  const int t = threadIdx.x;
  const int row = blockIdx.x * 16 + (t >> 4);   // b*C + c
  const int o = t & 15;
  const int b = row / CC;
  const int c = row - b * CC;
  float s = bias[c * CO + o];
  for (int q = 0; q < RS; ++q)
    s += part[(((size_t)q * CB + b) * CC + c) * CO + o];
  float n2 = s * s;
  #pragma unroll
  for (int m = 1; m < 16; m <<= 1) n2 += __shfl_xor(n2, m, 16);
  const float vv = s * n2 / (1.f + n2) * rsqrtf(n2 + 1e-8f);
  if (LAST) out[row * CO + o] = vv;
  else      vT[(c * CO + o) * CB + b] = vv;
}

// ---------------- agree: b_ij[r,c] (+)= (1/B) sum_{b,o} (W[r,c,o,:].x[b,r,:]) * v[b,c,o] ----------
// grid (C, R), thread = b
template<bool FIRST>
__global__ __launch_bounds__(256) void k_agree(const float* __restrict__ xT,
                                               const float* __restrict__ W,
                                               const float* __restrict__ vT,
                                               float* __restrict__ b_ij) {
  const int c = blockIdx.x;
  const int r = blockIdx.y;
  const int t = threadIdx.x;
  __shared__ float wsh[CO * CI];
  if (t < 32) ((float4*)wsh)[t] = ((const float4*)(W + ((size_t)r * CC + c) * CO * CI))[t];
  __syncthreads();
  const float4* xp = (const float4*)(xT + ((size_t)r * CB + t) * CI);
  const float4 x0 = xp[0], x1 = xp[1];
  float a = 0.f;
  #pragma unroll
  for (int o = 0; o < CO; ++o) {
    const float* wp = wsh + o * CI;
    float d = x0.x * wp[0];
    d = fmaf(x0.y, wp[1], d);
    d = fmaf(x0.z, wp[2], d);
    d = fmaf(x0.w, wp[3], d);
    d = fmaf(x1.x, wp[4], d);
    d = fmaf(x1.y, wp[5], d);
    d = fmaf(x1.z, wp[6], d);
    d = fmaf(x1.w, wp[7], d);
    a = fmaf(d, vT[(c * CO + o) * CB + t], a);
  }
  #pragma unroll
  for (int m = 1; m < 64; m <<= 1) a += __shfl_xor(a, m, 64);
  __shared__ float red[4];
  if ((t & 63) == 0) red[t >> 6] = a;
  __syncthreads();
  if (t == 0) {
    const float tot = (red[0] + red[1] + red[2] + red[3]) * (1.0f / CB);
    b_ij[r * CC + c] = FIRST ? tot : (b_ij[r * CC + c] + tot);
  }
}

extern "C" void kernel_launch(void* const* d_in, const int* in_sizes, int n_in,
                              void* d_out, int out_size, void* d_ws, size_t ws_size,
                              hipStream_t stream) {
  const float* x    = (const float*)d_in[0];
  const float* W    = (const float*)d_in[1];
  const float* bias = (const float*)d_in[2];
  float* out = (float*)d_out;

  // ws layout (floats): xT | part | vT | b_ij   (~17.6 MB total)
  float* xT   = (float*)d_ws;                       // R*B*I   = 2359296
  float* part = xT + (size_t)CR * CB * CI;          // RS*B*C*O = 1966080
  float* vT   = part + (size_t)RS * CB * CC * CO;   // C*O*B    = 40960
  float* b_ij = vT + (size_t)CC * CO * CB;          // R*C      = 11520

  k_transpose_x<<<(CB * CR * 2) / 256, 256, 0, stream>>>(x, xT);

  // iter 0 (uniform routing weights)
  k_s<0><<<dim3(CC, RS), 256, 0, stream>>>(xT, W, b_ij, part);
  k_squash<false><<<(CB * CC) / 16, 256, 0, stream>>>(part, bias, vT, out);
  k_agree<true><<<dim3(CC, CR), 256, 0, stream>>>(xT, W, vT, b_ij);

  // iter 1
  k_s<1><<<dim3(CC, RS), 256, 0, stream>>>(xT, W, b_ij, part);
  k_squash<false><<<(CB * CC) / 16, 256, 0, stream>>>(part, bias, vT, out);
  k_agree<false><<<dim3(CC, CR), 256, 0, stream>>>(xT, W, vT, b_ij);

  // iter 2 (final -> d_out)
  k_s<1><<<dim3(CC, RS), 256, 0, stream>>>(xT, W, b_ij, part);
  k_squash<true><<<(CB * CC) / 16, 256, 0, stream>>>(part, bias, vT, out);
}

// Round 2
// 106.722 us; speedup vs baseline: 2.3510x; 2.3510x over previous
//
#include <hip/hip_runtime.h>

#define CB 256   // batch
#define CR 1152  // routes
#define CC 10    // class capsules
#define CO 16    // out dim
#define CI 8     // in dim
#define CK (CR*CI)      // 9216 = contraction length (r,i)
#define KS 32           // K-split
#define KCHUNK (CK/KS)  // 288 k (= 9 MFMA steps of 32)
#define RCH (KCHUNK/CI) // 36 r's per chunk

typedef __bf16 bf16_t;
typedef __attribute__((ext_vector_type(8))) __bf16 bf16x8;
typedef __attribute__((ext_vector_type(4))) float f32x4;

// ---------- convert x (f32 [b][r][i] == [b][k]) and W (f32 [r][c][o][i] -> bf16 [c][o][k]) ----------
__global__ __launch_bounds__(256) void k_cvt(const float* __restrict__ x,
                                             const float* __restrict__ W,
                                             bf16_t* __restrict__ xb,
                                             bf16_t* __restrict__ Wt) {
  const int idx = blockIdx.x * 256 + threadIdx.x;
  const int NX = CB * CK / 8;      // 294912 x-vectors
  if (idx < NX) {
    const float4 f0 = ((const float4*)x)[idx * 2];
    const float4 f1 = ((const float4*)x)[idx * 2 + 1];
    bf16x8 o;
    o[0] = (bf16_t)f0.x; o[1] = (bf16_t)f0.y; o[2] = (bf16_t)f0.z; o[3] = (bf16_t)f0.w;
    o[4] = (bf16_t)f1.x; o[5] = (bf16_t)f1.y; o[6] = (bf16_t)f1.z; o[7] = (bf16_t)f1.w;
    ((bf16x8*)xb)[idx] = o;
  } else {
    const int wi = idx - NX;       // over C*O*R = 184320 (out-order: co major, r minor)
    if (wi < CC * CO * CR) {
      const int r = wi % CR;
      const int co = wi / CR;      // c*16+o
      const int c = co >> 4, o = co & 15;
      const float4* src = (const float4*)(W + (((size_t)r * CC + c) * CO + o) * CI);
      const float4 f0 = src[0], f1 = src[1];
      bf16x8 v;
      v[0] = (bf16_t)f0.x; v[1] = (bf16_t)f0.y; v[2] = (bf16_t)f0.z; v[3] = (bf16_t)f0.w;
      v[4] = (bf16_t)f1.x; v[5] = (bf16_t)f1.y; v[6] = (bf16_t)f1.z; v[7] = (bf16_t)f1.w;
      ((bf16x8*)Wt)[wi] = v;       // (co*CR + r)*8 bf16 = idx-NX vector slot
    }
  }
}

// ---------- s-pass via MFMA: part[ks][b][c][o] = sum_{k in chunk} xb[b,k] * c_ij[r(k),c] * Wt[c,o,k]
// grid (CC, KS, CB/64), block 256 = 4 waves, wave = one 16-row M-tile
template<int MODE>
__global__ __launch_bounds__(256) void k_s(const bf16_t* __restrict__ xb,
                                           const bf16_t* __restrict__ Wt,
                                           const float* __restrict__ b_ij,
                                           float* __restrict__ part) {
  const int c  = blockIdx.x;
  const int ks = blockIdx.y;
  const int t  = threadIdx.x;
  __shared__ float cs[RCH];
  if (t < RCH) {
    if (MODE == 0) {
      cs[t] = 1.0f / CC;
    } else {
      const float* bp = b_ij + (ks * RCH + t) * CC;
      float m = bp[0];
      #pragma unroll
      for (int k = 1; k < CC; ++k) m = fmaxf(m, bp[k]);
      float sum = 0.f;
      #pragma unroll
      for (int k = 0; k < CC; ++k) sum += __expf(bp[k] - m);
      cs[t] = __expf(bp[c] - m) / sum;
    }
  }
  __syncthreads();

  const int wid = t >> 6, lane = t & 63;
  const int mrow = lane & 15;          // A row / B col (=o)
  const int kg = lane >> 4;            // k-group 0..3
  const int b0 = blockIdx.z * 64 + wid * 16;
  const bf16x8* ap = (const bf16x8*)(xb + (size_t)(b0 + mrow) * CK + ks * KCHUNK) + kg;
  const bf16x8* bp = (const bf16x8*)(Wt + ((size_t)c * CO + mrow) * CK + ks * KCHUNK) + kg;

  f32x4 acc = {0.f, 0.f, 0.f, 0.f};
  #pragma unroll
  for (int s = 0; s < KCHUNK / 32; ++s) {
    bf16x8 a = ap[s * 4];
    bf16x8 w = bp[s * 4];
    const float cw = cs[s * 4 + kg];
    bf16x8 wsc;
    #pragma unroll
    for (int j = 0; j < 8; ++j) wsc[j] = (bf16_t)((float)w[j] * cw);
    acc = __builtin_amdgcn_mfma_f32_16x16x32_bf16(a, wsc, acc, 0, 0, 0);
  }

  const int o = lane & 15;
  const int rb = b0 + (lane >> 4) * 4;
  #pragma unroll
  for (int reg = 0; reg < 4; ++reg)
    part[(((size_t)ks * CB + (rb + reg)) * CC + c) * CO + o] = acc[reg];
}

// ---------- squash: reduce KS partials + bias ----------
template<bool LAST>
__global__ __launch_bounds__(256) void k_squash(const float* __restrict__ part,
                                                const float* __restrict__ bias,
                                                float* __restrict__ vT,
                                                float* __restrict__ out) {
  const int t = threadIdx.x;
  const int row = blockIdx.x * 16 + (t >> 4);   // b*CC + c
  const int o = t & 15;
  const int b = row / CC;
  const int c = row - b * CC;
  float s = bias[c * CO + o];
  #pragma unroll 8
  for (int q = 0; q < KS; ++q)
    s += part[(((size_t)q * CB + b) * CC + c) * CO + o];
  float n2 = s * s;
  #pragma unroll
  for (int m = 1; m < 16; m <<= 1) n2 += __shfl_xor(n2, m, 16);
  const float vv = s * n2 / (1.f + n2) * rsqrtf(n2 + 1e-8f);
  if (LAST) out[row * CO + o] = vv;
  else      vT[(c * CO + o) * CB + b] = vv;
}

// ---------- agree: b_ij[r,c] (+)= (1/B) sum_{b,o} (Wt[c,o,r*8:].xb[b,r*8:]) * v[b,c,o] ----------
template<bool FIRST>
__global__ __launch_bounds__(256) void k_agree(const bf16_t* __restrict__ xb,
                                               const bf16_t* __restrict__ Wt,
                                               const float* __restrict__ vT,
                                               float* __restrict__ b_ij) {
  const int c = blockIdx.x;
  const int r = blockIdx.y;
  const int t = threadIdx.x;
  __shared__ float wshf[CO][CI];
  __shared__ float red[4];
  if (t < CO) {
    bf16x8 w = *(const bf16x8*)(Wt + ((size_t)c * CO + t) * CK + (size_t)r * CI);
    #pragma unroll
    for (int j = 0; j < CI; ++j) wshf[t][j] = (float)w[j];
  }
  __syncthreads();
  bf16x8 xv = *(const bf16x8*)(xb + (size_t)t * CK + (size_t)r * CI);
  float xf[CI];
  #pragma unroll
  for (int j = 0; j < CI; ++j) xf[j] = (float)xv[j];
  float a = 0.f;
  #pragma unroll
  for (int o = 0; o < CO; ++o) {
    float d = xf[0] * wshf[o][0];
    #pragma unroll
    for (int j = 1; j < CI; ++j) d = fmaf(xf[j], wshf[o][j], d);
    a = fmaf(d, vT[(c * CO + o) * CB + t], a);
  }
  #pragma unroll
  for (int m = 1; m < 64; m <<= 1) a += __shfl_xor(a, m);
  if ((t & 63) == 0) red[t >> 6] = a;
  __syncthreads();
  if (t == 0) {
    const float tot = (red[0] + red[1] + red[2] + red[3]) * (1.0f / CB);
    b_ij[r * CC + c] = FIRST ? tot : (b_ij[r * CC + c] + tot);
  }
}

extern "C" void kernel_launch(void* const* d_in, const int* in_sizes, int n_in,
                              void* d_out, int out_size, void* d_ws, size_t ws_size,
                              hipStream_t stream) {
  const float* x    = (const float*)d_in[0];
  const float* W    = (const float*)d_in[1];
  const float* bias = (const float*)d_in[2];
  float* out = (float*)d_out;

  // ws layout: xb (bf16) | Wt (bf16) | part | vT | b_ij   (~13.1 MB)
  bf16_t* xb = (bf16_t*)d_ws;                         // B*K      = 2359296 bf16
  bf16_t* Wt = xb + (size_t)CB * CK;                  // C*O*K    = 1474560 bf16
  float*  part = (float*)(Wt + (size_t)CC * CO * CK); // KS*B*C*O = 1310720 f32
  float*  vT   = part + (size_t)KS * CB * CC * CO;    // C*O*B    = 40960 f32
  float*  b_ij = vT + (size_t)CC * CO * CB;           // R*C      = 11520 f32

  const int ncvt = (CB * CK / 8) + CC * CO * CR;      // 294912 + 184320
  k_cvt<<<(ncvt + 255) / 256, 256, 0, stream>>>(x, W, xb, Wt);

  // iter 0 (uniform c_ij)
  k_s<0><<<dim3(CC, KS, CB / 64), 256, 0, stream>>>(xb, Wt, b_ij, part);
  k_squash<false><<<(CB * CC) / 16, 256, 0, stream>>>(part, bias, vT, out);
  k_agree<true><<<dim3(CC, CR), 256, 0, stream>>>(xb, Wt, vT, b_ij);

  // iter 1
  k_s<1><<<dim3(CC, KS, CB / 64), 256, 0, stream>>>(xb, Wt, b_ij, part);
  k_squash<false><<<(CB * CC) / 16, 256, 0, stream>>>(part, bias, vT, out);
  k_agree<false><<<dim3(CC, CR), 256, 0, stream>>>(xb, Wt, vT, b_ij);

  // iter 2 (final -> d_out)
  k_s<1><<<dim3(CC, KS, CB / 64), 256, 0, stream>>>(xb, Wt, b_ij, part);
  k_squash<true><<<(CB * CC) / 16, 256, 0, stream>>>(part, bias, vT, out);
}

// Round 4
// 88.454 us; speedup vs baseline: 2.8366x; 1.2065x over previous
//
#include <hip/hip_runtime.h>

#define CB 256   // batch
#define CR 1152  // routes
#define CC 10    // class capsules
#define CO 16    // out dim
#define CI 8     // in dim
#define CK (CR*CI)   // 9216 contraction length for s-pass
#define NCO (CC*CO)  // 160

typedef __bf16 bf16_t;
typedef __attribute__((ext_vector_type(8))) __bf16 bf16x8;
typedef __attribute__((ext_vector_type(4))) float f32x4;

// ---------------- cvt: x -> xb [b][k] bf16, xTb [k][b] bf16 ; W -> Wt [co][k] bf16 ----------------
__global__ __launch_bounds__(256) void k_cvt(const float* __restrict__ x,
                                             const float* __restrict__ W,
                                             bf16_t* __restrict__ xb,
                                             bf16_t* __restrict__ xTb,
                                             bf16_t* __restrict__ Wt) {
  const int t = threadIdx.x;
  if (blockIdx.x < 1152) {
    // x tile job: 144 k-tiles x 8 b-tiles; tile = 32 b x 64 k
    const int bt = blockIdx.x & 7, kt = blockIdx.x >> 3;
    const int b0 = bt * 32, k0 = kt * 64;
    __shared__ float ldsT[64][33];
    const int row = t >> 3, cv = t & 7;   // row 0..31, cv 0..7 (8 k each)
    const float4* xp = (const float4*)(x + (size_t)(b0 + row) * CK + k0 + cv * 8);
    const float4 f0 = xp[0], f1 = xp[1];
    float vals[8] = {f0.x, f0.y, f0.z, f0.w, f1.x, f1.y, f1.z, f1.w};
    bf16x8 ov;
    #pragma unroll
    for (int j = 0; j < 8; ++j) {
      ov[j] = (bf16_t)vals[j];
      ldsT[cv * 8 + j][row] = vals[j];
    }
    *(bf16x8*)(xb + (size_t)(b0 + row) * CK + k0 + cv * 8) = ov;
    __syncthreads();
    const int kr = t >> 2, bs = t & 3;    // kr 0..63, bs 0..3 (8 b each)
    bf16x8 tv;
    #pragma unroll
    for (int j = 0; j < 8; ++j) tv[j] = (bf16_t)ldsT[kr][bs * 8 + j];
    *(bf16x8*)(xTb + (size_t)(k0 + kr) * CB + b0 + bs * 8) = tv;
  } else {
    // W job: 720 blocks, wi over C*O*R = 184320
    const int wi = (blockIdx.x - 1152) * 256 + t;
    const int r = wi % CR;
    const int co = wi / CR;
    const int c = co >> 4, o = co & 15;
    const float4* src = (const float4*)(W + (((size_t)r * CC + c) * CO + o) * CI);
    const float4 f0 = src[0], f1 = src[1];
    bf16x8 v;
    v[0] = (bf16_t)f0.x; v[1] = (bf16_t)f0.y; v[2] = (bf16_t)f0.z; v[3] = (bf16_t)f0.w;
    v[4] = (bf16_t)f1.x; v[5] = (bf16_t)f1.y; v[6] = (bf16_t)f1.z; v[7] = (bf16_t)f1.w;
    *(bf16x8*)(Wt + (size_t)co * CK + r * 8) = v;
  }
}

// ---------------- fused s + squash: grid (16 btiles, 10 c), block 512 = 8 waves splitting K ----------
// s[b,c,o] = sum_k xb[b,k] * Bmat[c,o,k]  (Bmat pre-scaled by c_ij except MODE0: * 0.1)
template<int MODE, bool LAST>
__global__ __launch_bounds__(512) void k_s(const bf16_t* __restrict__ xb,
                                           const bf16_t* __restrict__ Bmat,
                                           const float* __restrict__ bias,
                                           bf16_t* __restrict__ vTb,
                                           float* __restrict__ out) {
  const int bt = blockIdx.x, c = blockIdx.y;
  const int t = threadIdx.x;
  const int w = t >> 6, lane = t & 63;
  const int mrow = lane & 15, kg = lane >> 4;
  const int b0 = bt * 16;
  const size_t kbase = (size_t)w * (CK / 8);   // 1152 k per wave = 36 ksteps

  const bf16x8* ap = (const bf16x8*)(xb + (size_t)(b0 + mrow) * CK + kbase) + kg;
  const bf16x8* bp = (const bf16x8*)(Bmat + (size_t)(c * CO + mrow) * CK + kbase) + kg;

  f32x4 acc0 = {0.f, 0.f, 0.f, 0.f}, acc1 = {0.f, 0.f, 0.f, 0.f};
  #pragma unroll 6
  for (int s = 0; s < 36; s += 2) {
    acc0 = __builtin_amdgcn_mfma_f32_16x16x32_bf16(ap[s * 4], bp[s * 4], acc0, 0, 0, 0);
    acc1 = __builtin_amdgcn_mfma_f32_16x16x32_bf16(ap[(s + 1) * 4], bp[(s + 1) * 4], acc1, 0, 0, 0);
  }
  const f32x4 acc = acc0 + acc1;

  __shared__ float Ls[8][64][4];
  #pragma unroll
  for (int reg = 0; reg < 4; ++reg) Ls[w][lane][reg] = acc[reg];
  __syncthreads();

  if (t < 256) {
    const int row = t >> 4, col = t & 15;          // row = b-local, col = o
    const int l = ((row >> 2) << 4) | col, reg = row & 3;
    float s = 0.f;
    #pragma unroll
    for (int q = 0; q < 8; ++q) s += Ls[q][l][reg];
    if (MODE == 0) s *= 0.1f;                      // uniform c_ij = 1/10
    s += bias[c * CO + col];
    float n2 = s * s;
    #pragma unroll
    for (int m = 1; m < 16; m <<= 1) n2 += __shfl_xor(n2, m);
    const float vv = s * n2 / (1.f + n2) * rsqrtf(n2 + 1e-8f);
    if (LAST) out[(size_t)(b0 + row) * NCO + c * CO + col] = vv;
    else      vTb[(size_t)(c * CO + col) * CB + b0 + row] = (bf16_t)vv;
  }
}

// ---------------- agree + softmax + W-prescale: grid 144 blocks (8 r's each), block 256 = 4 waves ----
// G[(r,i),(c,o)] = sum_b xTb[(r,i)][b] * vTb[(c,o)][b]  via MFMA (K=256)
// agree[r,c] = (1/B) sum_{i,o} W[r,c,o,i]*G ; b_ij += agree ; cw = softmax(b_ij) ; Wts = Wt*cw
template<bool FIRST>
__global__ __launch_bounds__(256) void k_asc(const bf16_t* __restrict__ xTb,
                                             const bf16_t* __restrict__ vTb,
                                             const float* __restrict__ W,
                                             const bf16_t* __restrict__ Wt,
                                             float* __restrict__ b_ij,
                                             bf16_t* __restrict__ Wts) {
  const int r0 = blockIdx.x * 8;
  const int t = threadIdx.x;
  const int w = t >> 6, lane = t & 63;
  const int mrow = lane & 15, kg = lane >> 4;

  __shared__ __align__(16) unsigned short vL[NCO][CB + 8];  // bf16, +16B pad per row
  __shared__ float agrL[8][CC];
  __shared__ float cwL[8][CC];

  // stage all of vTb (80 KB = 5120 bf16x8 vectors) into LDS
  #pragma unroll
  for (int q = 0; q < 20; ++q) {
    const int idx = q * 256 + t;          // 5120 bf16x8 vectors
    const int co = idx >> 5, bs = idx & 31;
    const bf16x8 v = ((const bf16x8*)vTb)[idx];
    *(bf16x8*)&vL[co][bs * 8] = v;
  }

  // A fragments: full K=256, rows (r,i) for this wave's 2 r's
  const int m0 = r0 * 8 + w * 16;
  const bf16x8* ap = (const bf16x8*)(xTb + (size_t)(m0 + mrow) * CB) + kg;
  bf16x8 a[8];
  #pragma unroll
  for (int s = 0; s < 8; ++s) a[s] = ap[s * 4];
  __syncthreads();

  const int o = lane & 15, g = lane >> 4;
  for (int c = 0; c < CC; ++c) {
    f32x4 acc = {0.f, 0.f, 0.f, 0.f};
    #pragma unroll
    for (int s = 0; s < 8; ++s) {
      const bf16x8 bv = *(const bf16x8*)&vL[c * CO + mrow][s * 32 + kg * 8];
      acc = __builtin_amdgcn_mfma_f32_16x16x32_bf16(a[s], bv, acc, 0, 0, 0);
    }
    float p = 0.f;
    #pragma unroll
    for (int reg = 0; reg < 4; ++reg) {
      const int m = g * 4 + reg, rl = m >> 3, i = m & 7;
      p += acc[reg] * W[(((size_t)(r0 + w * 2 + rl) * CC + c) * CO + o) * CI + i];
    }
    #pragma unroll
    for (int msk = 1; msk < 32; msk <<= 1) p += __shfl_xor(p, msk);
    if ((lane & 31) == 0) agrL[w * 2 + (lane >> 5)][c] = p * (1.0f / CB);
  }
  __syncthreads();

  if (t < 8) {
    const int r = r0 + t;
    float nb[CC];
    float mx = -1e30f;
    #pragma unroll
    for (int c = 0; c < CC; ++c) {
      nb[c] = (FIRST ? 0.f : b_ij[r * CC + c]) + agrL[t][c];
      mx = fmaxf(mx, nb[c]);
    }
    float sum = 0.f;
    #pragma unroll
    for (int c = 0; c < CC; ++c) {
      b_ij[r * CC + c] = nb[c];
      const float e = __expf(nb[c] - mx);
      cwL[t][c] = e;
      sum += e;
    }
    const float inv = 1.f / sum;
    #pragma unroll
    for (int c = 0; c < CC; ++c) cwL[t][c] *= inv;
  }
  __syncthreads();

  // Wts[co][k] = Wt[co][k] * cw[r(k), c(co)] for this block's 8 r's (1280 bf16x8 slots)
  #pragma unroll
  for (int q = 0; q < 5; ++q) {
    const int slot = q * 256 + t;
    const int co = slot >> 3, rl = slot & 7;
    const float cw = cwL[rl][co >> 4];
    const size_t off = (size_t)co * CK + (r0 + rl) * 8;
    const bf16x8 wv = *(const bf16x8*)(Wt + off);
    bf16x8 ov;
    #pragma unroll
    for (int j = 0; j < 8; ++j) ov[j] = (bf16_t)((float)wv[j] * cw);
    *(bf16x8*)(Wts + off) = ov;
  }
}

extern "C" void kernel_launch(void* const* d_in, const int* in_sizes, int n_in,
                              void* d_out, int out_size, void* d_ws, size_t ws_size,
                              hipStream_t stream) {
  const float* x    = (const float*)d_in[0];
  const float* W    = (const float*)d_in[1];
  const float* bias = (const float*)d_in[2];
  float* out = (float*)d_out;

  // ws: xb | xTb | Wt | Wts | vTb (bf16) | b_ij (f32)  ~15.5 MB
  bf16_t* xb  = (bf16_t*)d_ws;
  bf16_t* xTb = xb  + (size_t)CB * CK;
  bf16_t* Wt  = xTb + (size_t)CB * CK;
  bf16_t* Wts = Wt  + (size_t)NCO * CK;
  bf16_t* vTb = Wts + (size_t)NCO * CK;
  float*  b_ij = (float*)(vTb + (size_t)NCO * CB);

  k_cvt<<<1872, 256, 0, stream>>>(x, W, xb, xTb, Wt);

  // iter 0: uniform c_ij (0.1 post-scale), then agree+softmax+prescale
  k_s<0, false><<<dim3(16, 10), 512, 0, stream>>>(xb, Wt, bias, vTb, out);
  k_asc<true><<<144, 256, 0, stream>>>(xTb, vTb, W, Wt, b_ij, Wts);

  // iter 1
  k_s<1, false><<<dim3(16, 10), 512, 0, stream>>>(xb, Wts, bias, vTb, out);
  k_asc<false><<<144, 256, 0, stream>>>(xTb, vTb, W, Wt, b_ij, Wts);

  // iter 2 (final)
  k_s<1, true><<<dim3(16, 10), 512, 0, stream>>>(xb, Wts, bias, vTb, out);
}